// Round 11
// baseline (283.059 us; speedup 1.0000x reference)
//
#include <hip/hip_runtime.h>

// ---------------------------------------------------------------------------
// MultiHeadAttention forward, MI355X/gfx950.
// B=2, T=2048, D=2048, H=16, Dh=128. fp32 in/out, bf16 MFMA internally.
// Reference quirks (faithful): multiplicative tril mask (masked scores = 0,
// NOT -inf -> exp(0)=1 contributions over ALL 2048 cols), scale = 1/sqrt(T).
// Round 11: QKV GEMM -> faithful m201-class 8-phase port: BM=BN=256, BK=64,
// 8 waves (2Mx4N, wave tile 128x64), 128KB dbuf LDS. Per K-tile: entry
// {stage(kt+1) -> vmcnt(8) -> barrier} then 4 phases, each {reads -> barrier
// -> lgkmcnt(0)+sched_barrier(0) -> setprio -> 16 MFMA -> setprio -> barrier}.
// vmcnt never drains to 0 until the final tile. Wo + attn unchanged.
// ---------------------------------------------------------------------------

typedef __attribute__((ext_vector_type(4))) float  f32x4;
typedef __attribute__((ext_vector_type(8))) short  bf16x8;
typedef __attribute__((ext_vector_type(4))) unsigned short u16x4;

#define AS1 __attribute__((address_space(1)))
#define AS3 __attribute__((address_space(3)))

__device__ __forceinline__ void llds16(const void* g, void* l) {
  __builtin_amdgcn_global_load_lds((const AS1 void*)g, (AS3 void*)l, 16, 0, 0);
}

__device__ __forceinline__ unsigned short f2bf(float f) {   // RNE
  unsigned int u = __builtin_bit_cast(unsigned int, f);
  u += 0x7fffu + ((u >> 16) & 1u);
  return (unsigned short)(u >> 16);
}

__device__ __forceinline__ unsigned short f2bfru(float f) { // round-half-up
  return (unsigned short)((__builtin_bit_cast(unsigned int, f) + 0x8000u) >> 16);
}

__device__ __forceinline__ float bf2f(unsigned short u) {
  return __builtin_bit_cast(float, (unsigned int)u << 16);
}

// ---------------------------------------------------------------------------
// cast x (fp32) -> bf16, 4 elements/thread
// ---------------------------------------------------------------------------
__global__ __launch_bounds__(256) void cast_x_kernel(const float* __restrict__ in,
                                                     unsigned short* __restrict__ out) {
  int i = blockIdx.x * 256 + threadIdx.x;
  f32x4 v = ((const f32x4*)in)[i];
  u16x4 o;
  o[0] = f2bf(v[0]); o[1] = f2bf(v[1]); o[2] = f2bf(v[2]); o[3] = f2bf(v[3]);
  ((u16x4*)out)[i] = o;
}

// ---------------------------------------------------------------------------
// 4 weight transposes in one launch. W [2048][2048] fp32 -> Wt[n][k] bf16.
// ---------------------------------------------------------------------------
__global__ __launch_bounds__(256) void transpose_w4_kernel(
    const float* __restrict__ W0, const float* __restrict__ W1,
    const float* __restrict__ W2, const float* __restrict__ W3,
    unsigned short* __restrict__ T0, unsigned short* __restrict__ T1,
    unsigned short* __restrict__ T2, unsigned short* __restrict__ T3) {
  __shared__ float tile[32][33];
  const int z = blockIdx.z;
  const float* W = (z == 0) ? W0 : (z == 1) ? W1 : (z == 2) ? W2 : W3;
  unsigned short* Wt = (z == 0) ? T0 : (z == 1) ? T1 : (z == 2) ? T2 : T3;
  const int bx = blockIdx.x << 5;   // k base
  const int by = blockIdx.y << 5;   // n base
  const int tx = threadIdx.x;       // 0..31
  const int ty = threadIdx.y;       // 0..7
#pragma unroll
  for (int r = ty; r < 32; r += 8)
    tile[r][tx] = W[(size_t)(bx + r) * 2048 + by + tx];
  __syncthreads();
#pragma unroll
  for (int r = ty; r < 32; r += 8)
    Wt[(size_t)(by + r) * 2048 + bx + tx] = f2bf(tile[tx][r]);
}

// ---------------------------------------------------------------------------
// Fused QKV projection GEMM, 8-phase (m201-class).
// C[M=4096][N=6144] = X[M][K=2048] @ Wt[N][K]^T, Wt = [Wq^T|Wk^T|Wv^T].
// BM=BN=256, BK=64. 512 thr / 8 waves (2M x 4N), wave tile 128x64
// (8mi x 4ni), acc 128 VGPR. LDS: dbuf x (A 32KB + B 32KB) = 128KB.
// K-tile entry: stage(kt+1) [overwrites kt-1's buffer: all reads confirmed
// by kt-1's final barrier] -> vmcnt(8) [kt's 8 loads landed; kt+1's 8 stay
// in flight] -> barrier. Then 4 phases:
//   P1: read A[mi0-3,ks0](4) + B[ni,ks0](4) | P2: read A[mi4-7,ks0](4)
//   P3: read A[mi0-3,ks1](4) + B[ni,ks1](4) | P4: read A[mi4-7,ks1](4)
// each: reads -> BAR -> lgkmcnt(0)+sched_barrier(0) -> setprio(1) ->
// 16 MFMA -> setprio(0) -> BAR.
// Rows 128B = 8 chunks of 16B, chunk c ^= row&7 both sides (<=2-way).
// Grid 384 flat; 3 bn panels per XCD (3MB -> L2).
// Epilogue: region 0 -> Qb * 1/sqrt(T), 1 -> Kb, 2 -> Vt scatter.
// ---------------------------------------------------------------------------
__global__ __launch_bounds__(512, 2) void gemm_qkv8p(const unsigned short* __restrict__ A,
                                                     const unsigned short* __restrict__ Bt,
                                                     unsigned short* __restrict__ Qb,
                                                     unsigned short* __restrict__ Kb,
                                                     unsigned short* __restrict__ Vt) {
  __shared__ __align__(16) char smem[131072];   // 2 x (A 32KB | B 32KB)
  const int tid  = threadIdx.x;
  const int lane = tid & 63;
  const int w    = tid >> 6;          // 0..7
  const int wr   = w >> 2;            // m-half (0..1): rows wr*128..+128
  const int wc   = w & 3;             // n-quarter (0..3): cols wc*64..+64
  const int q16  = lane >> 4;
  const int l15  = lane & 15;
  const int f    = blockIdx.x;        // 0..383
  const int xcd  = f & 7;
  const int idx  = f >> 3;            // 0..47
  const int bn   = xcd * 3 + (idx % 3);   // 0..23
  const int bm   = idx / 3;               // 0..15

  // staging sources (pre-swizzled; LDS dest linear). 128B rows = 8 x 16B
  // chunks; phys chunk = tid&7, logical = phys ^ (row&7), row = ro*64+tid>>3.
  const int t8 = tid >> 3;            // 0..63
  const int tswz = ((tid & 7) ^ (t8 & 7)) << 3;    // element offset in row
  const unsigned short* aS = A  + (size_t)((bm << 8) + t8) * 2048 + tswz;
  const unsigned short* bS = Bt + (size_t)((bn << 8) + t8) * 2048 + tswz;
  const int sdst = tid << 4;

  auto stage = [&](int kt, char* buf) {
    const size_t ko = (size_t)kt << 6;
#pragma unroll
    for (int ro = 0; ro < 4; ++ro)
      llds16(aS + (size_t)(ro << 6) * 2048 + ko, buf + (ro << 13) + sdst);
#pragma unroll
    for (int ro = 0; ro < 4; ++ro)
      llds16(bS + (size_t)(ro << 6) * 2048 + ko, buf + 32768 + (ro << 13) + sdst);
  };

  // ds_read offsets: frag (row-block, ks): lane reads row = base + l15,
  // chunk = (ks*4 + q16) ^ (l15&7)  ->  <=2-way bank aliasing.
  const int c0   = (q16 ^ (l15 & 7)) << 4;               // ks1: ^ 64
  const int aRow = ((wr << 7) + l15) << 7;               // + mi*2048
  const int bRow = 32768 + (((wc << 6) + l15) << 7);     // + ni*2048

  f32x4 acc[8][4];
#pragma unroll
  for (int i = 0; i < 8; ++i)
#pragma unroll
    for (int j = 0; j < 4; ++j) acc[i][j] = (f32x4){0.f, 0.f, 0.f, 0.f};

#define LGKM0() do { asm volatile("s_waitcnt lgkmcnt(0)" ::: "memory"); \
                     __builtin_amdgcn_sched_barrier(0); } while (0)
#define BAR()   __builtin_amdgcn_s_barrier()

  // prologue: tile 0 staged into buf0
  stage(0, smem);

#pragma unroll 1
  for (int kt = 0; kt < 32; ++kt) {
    char* buf = smem + ((kt & 1) << 16);
    if (kt < 31) {
      stage(kt + 1, smem + (((kt + 1) & 1) << 16));
      asm volatile("s_waitcnt vmcnt(8)" ::: "memory");   // kt's 8 landed
    } else {
      asm volatile("s_waitcnt vmcnt(0)" ::: "memory");
    }
    BAR();

    bf16x8 af[4], ag[4], bf0[4], bf1[4];
    // ---- P1: A[mi0-3, ks0] + B[ks0]; MFMA mi0-3 x ni x ks0 ----
#pragma unroll
    for (int mi = 0; mi < 4; ++mi)
      af[mi] = *(const bf16x8*)(buf + aRow + (mi << 11) + c0);
#pragma unroll
    for (int ni = 0; ni < 4; ++ni)
      bf0[ni] = *(const bf16x8*)(buf + bRow + (ni << 11) + c0);
    BAR(); LGKM0();
    __builtin_amdgcn_s_setprio(1);
#pragma unroll
    for (int mi = 0; mi < 4; ++mi)
#pragma unroll
      for (int ni = 0; ni < 4; ++ni)
        acc[mi][ni] = __builtin_amdgcn_mfma_f32_16x16x32_bf16(af[mi], bf0[ni], acc[mi][ni], 0, 0, 0);
    __builtin_amdgcn_s_setprio(0);
    BAR();
    // ---- P2: A[mi4-7, ks0]; MFMA mi4-7 x ni x ks0 ----
#pragma unroll
    for (int mi = 0; mi < 4; ++mi)
      ag[mi] = *(const bf16x8*)(buf + aRow + ((mi + 4) << 11) + c0);
    BAR(); LGKM0();
    __builtin_amdgcn_s_setprio(1);
#pragma unroll
    for (int mi = 0; mi < 4; ++mi)
#pragma unroll
      for (int ni = 0; ni < 4; ++ni)
        acc[mi + 4][ni] = __builtin_amdgcn_mfma_f32_16x16x32_bf16(ag[mi], bf0[ni], acc[mi + 4][ni], 0, 0, 0);
    __builtin_amdgcn_s_setprio(0);
    BAR();
    // ---- P3: A[mi0-3, ks1] + B[ks1]; MFMA mi0-3 x ni x ks1 ----
#pragma unroll
    for (int mi = 0; mi < 4; ++mi)
      af[mi] = *(const bf16x8*)(buf + aRow + (mi << 11) + (c0 ^ 64));
#pragma unroll
    for (int ni = 0; ni < 4; ++ni)
      bf1[ni] = *(const bf16x8*)(buf + bRow + (ni << 11) + (c0 ^ 64));
    BAR(); LGKM0();
    __builtin_amdgcn_s_setprio(1);
#pragma unroll
    for (int mi = 0; mi < 4; ++mi)
#pragma unroll
      for (int ni = 0; ni < 4; ++ni)
        acc[mi][ni] = __builtin_amdgcn_mfma_f32_16x16x32_bf16(af[mi], bf1[ni], acc[mi][ni], 0, 0, 0);
    __builtin_amdgcn_s_setprio(0);
    BAR();
    // ---- P4: A[mi4-7, ks1]; MFMA mi4-7 x ni x ks1 ----
#pragma unroll
    for (int mi = 0; mi < 4; ++mi)
      ag[mi] = *(const bf16x8*)(buf + aRow + ((mi + 4) << 11) + (c0 ^ 64));
    BAR(); LGKM0();
    __builtin_amdgcn_s_setprio(1);
#pragma unroll
    for (int mi = 0; mi < 4; ++mi)
#pragma unroll
      for (int ni = 0; ni < 4; ++ni)
        acc[mi + 4][ni] = __builtin_amdgcn_mfma_f32_16x16x32_bf16(ag[mi], bf1[ni], acc[mi + 4][ni], 0, 0, 0);
    __builtin_amdgcn_s_setprio(0);
    BAR();
  }

#undef LGKM0
#undef BAR

  // epilogue. C/D layout: col = lane&15, row = (lane>>4)*4 + reg  [m89]
  const float qscale = 0.02209708691207961f;   // 1/sqrt(2048)
  const int rb = q16 << 2;
#pragma unroll
  for (int mi = 0; mi < 8; ++mi) {
    int m0 = (bm << 8) + (wr << 7) + (mi << 4) + rb;
#pragma unroll
    for (int ni = 0; ni < 4; ++ni) {
      int gn = (bn << 8) + (wc << 6) + (ni << 4) + l15;
      int region = gn >> 11;                     // 0 Q, 1 K, 2 V
      int nloc = gn & 2047;
      if (region == 0) {
#pragma unroll
        for (int j = 0; j < 4; ++j)
          Qb[(size_t)(m0 + j) * 2048 + nloc] = f2bf(acc[mi][ni][j] * qscale);
      } else if (region == 1) {
#pragma unroll
        for (int j = 0; j < 4; ++j)
          Kb[(size_t)(m0 + j) * 2048 + nloc] = f2bf(acc[mi][ni][j]);
      } else {
        u16x4 pk;
#pragma unroll
        for (int j = 0; j < 4; ++j) pk[j] = f2bf(acc[mi][ni][j]);
        int b = m0 >> 11, t = m0 & 2047;
        *(u16x4*)(Vt + ((size_t)((b << 4) + (nloc >> 7)) * 128 + (nloc & 127)) * 2048 + t) = pk;
      }
    }
  }
}

// ---------------------------------------------------------------------------
// Wo GEMM (round-6 structure, passing): C fp32 = A[M][K] @ Bt[N][K]^T.
// BM=128, BN=128, wave tile 64x64 (2Mx2N), 4 waves, BK=32, ring-3 LDS,
// 1 barrier + vmcnt(4)/step. Grid 512 (2 blocks/CU).
// ---------------------------------------------------------------------------
__global__ __launch_bounds__(256, 2) void gemm_wo(const unsigned short* __restrict__ A,
                                                  const unsigned short* __restrict__ Bt,
                                                  float* __restrict__ Co) {
  constexpr int SLOT = 8192 + 8192;
  __shared__ __align__(16) char smem[3 * SLOT];

  const int tid  = threadIdx.x;
  const int lane = tid & 63;
  const int w    = tid >> 6;                        // 0..3
  const int q16  = lane >> 4;
  const int l15  = lane & 15;
  const int f    = blockIdx.x;
  const int g    = f >> 3;
  const int bn   = ((f & 7) << 1) + (g & 1);
  const int bm   = g >> 1;
  const int wmb  = (w >> 1) << 6;
  const int wnb  = (w & 1) << 6;

  f32x4 acc[4][4];
#pragma unroll
  for (int i = 0; i < 4; ++i)
#pragma unroll
    for (int j = 0; j < 4; ++j) acc[i][j] = (f32x4){0.f, 0.f, 0.f, 0.f};

  const int rowA = tid >> 2;
  const int chA  = tid & 3;
  auto stageT = [&](int t, char* sb) {
    const int k0 = t << 5;
#pragma unroll
    for (int r = 0; r < 2; ++r) {
      int row = (r << 6) + rowA;
      const unsigned short* src = A + (size_t)((bm << 7) + row) * 2048 + k0
                                    + ((chA ^ ((row >> 1) & 3)) << 3);
      llds16(src, sb + (r << 12) + (w << 10));
    }
#pragma unroll
    for (int r = 0; r < 2; ++r) {
      int row = (r << 6) + rowA;
      const unsigned short* src = Bt + (size_t)((bn << 7) + row) * 2048 + k0
                                     + ((chA ^ ((row >> 1) & 3)) << 3);
      llds16(src, sb + 8192 + (r << 12) + (w << 10));
    }
  };

  auto computeT = [&](const char* base) {
    bf16x8 af[4], bf[4];
#pragma unroll
    for (int mi = 0; mi < 4; ++mi) {
      int row = wmb + (mi << 4) + l15;
      af[mi] = *(const bf16x8*)(base + (row << 6) + ((q16 ^ ((row >> 1) & 3)) << 4));
    }
#pragma unroll
    for (int ni = 0; ni < 4; ++ni) {
      int row = wnb + (ni << 4) + l15;
      bf[ni] = *(const bf16x8*)(base + 8192 + (row << 6) + ((q16 ^ ((row >> 1) & 3)) << 4));
    }
    __builtin_amdgcn_s_setprio(1);
#pragma unroll
    for (int mi = 0; mi < 4; ++mi)
#pragma unroll
      for (int ni = 0; ni < 4; ++ni)
        acc[mi][ni] = __builtin_amdgcn_mfma_f32_16x16x32_bf16(af[mi], bf[ni], acc[mi][ni], 0, 0, 0);
    __builtin_amdgcn_s_setprio(0);
  };

  auto STEP = [&](int t, char* cbase, char* sbase) {
    asm volatile("s_waitcnt vmcnt(4)" ::: "memory");
    __builtin_amdgcn_s_barrier();
    stageT(t + 2, sbase);
    computeT(cbase);
  };

  char* s0 = smem;
  char* s1 = smem + SLOT;
  char* s2 = smem + 2 * SLOT;

  stageT(0, s0); stageT(1, s1);
#pragma unroll 1
  for (int t = 0; t < 60; t += 3) {
    STEP(t,     s0, s2);
    STEP(t + 1, s1, s0);
    STEP(t + 2, s2, s1);
  }
  STEP(60, s0, s2);
  STEP(61, s1, s0);
  asm volatile("s_waitcnt vmcnt(4)" ::: "memory");
  __builtin_amdgcn_s_barrier();
  computeT(s2);
  asm volatile("s_waitcnt vmcnt(0)" ::: "memory");
  __builtin_amdgcn_s_barrier();
  computeT(s0);

  const int rb = q16 << 2;
#pragma unroll
  for (int mi = 0; mi < 4; ++mi) {
    int m0 = (bm << 7) + wmb + (mi << 4) + rb;
#pragma unroll
    for (int ni = 0; ni < 4; ++ni) {
      int n = (bn << 7) + wnb + (ni << 4) + l15;
#pragma unroll
      for (int j = 0; j < 4; ++j)
        Co[(size_t)(m0 + j) * 2048 + n] = acc[mi][ni][j];
    }
  }
}

// ---------------------------------------------------------------------------
// V suffix sums at 32-row granularity.
// Suf[j][bh][d] = sum_{s >= 32j} V[b, s, h, d],  j in 0..64 (Suf[64] = 0).
// ---------------------------------------------------------------------------
__global__ __launch_bounds__(256) void vsuf_kernel(const unsigned short* __restrict__ Vt,
                                                   float* __restrict__ Suf) {
  const int row  = blockIdx.x * 4 + (threadIdx.x >> 6);  // 0..4095
  const int lane = threadIdx.x & 63;
  const unsigned short* vp = Vt + (size_t)row * 2048 + (lane << 5);
  float a = 0.f;
#pragma unroll
  for (int c = 0; c < 4; ++c) {
    bf16x8 v = *(const bf16x8*)(vp + (c << 3));
#pragma unroll
    for (int j = 0; j < 8; ++j) a += bf2f((unsigned short)v[j]);
  }
  float I = a;
#pragma unroll
  for (int off = 1; off < 64; off <<= 1) {
    float t = __shfl_down(I, off, 64);
    I += (lane + off < 64) ? t : 0.f;
  }
  Suf[(size_t)lane * 4096 + row] = I;
  if (lane == 0) Suf[(size_t)64 * 4096 + row] = 0.f;
}

// ---------------------------------------------------------------------------
// Fused attention, causal-skipped. Flat grid 1024; decode:
//   xcd = f&7, bh = xcd*4 + ((f>>3)&3), strip = 31 - (f>>5)  (LPT order)
// Q is PRE-SCALED by 1/sqrt(T). Mask only on the straddling tile. Tiles
// above the diagonal covered by V-suffix sums (p == 1 exactly there).
// ---------------------------------------------------------------------------
__global__ __launch_bounds__(256) void attn_kernel(const unsigned short* __restrict__ Q,
                                                   const unsigned short* __restrict__ K,
                                                   const unsigned short* __restrict__ V,  // Vt layout
                                                   const float* __restrict__ Suf,
                                                   unsigned short* __restrict__ O) {
  __shared__ __align__(16) char smem[36864];  // K dbuf 2x8K | V dbuf 2x8K | P 4x1K
  const int tid  = threadIdx.x;
  const int lane = tid & 63;
  const int w    = tid >> 6;
  const int q16  = lane >> 4;
  const int l15  = lane & 15;
  const int f    = blockIdx.x;
  const int bh    = ((f & 7) << 2) + ((f >> 3) & 3);
  const int strip = 31 - (f >> 5);
  const int b  = bh >> 4;
  const size_t qkbase = ((size_t)(b << 11)) * 2048 + ((size_t)(bh & 15) << 7);
  const size_t vbase  = (size_t)bh << 18;     // bh*128*2048
  const int rb = q16 << 2;
  char* Psm = smem + 32768 + (w << 10);

  const int numIter = 2 * strip + 2;
  const int t0 = (strip << 6) + (w << 4);

  auto stage = [&](int s0, int kb, int vb) {
#pragma unroll
    for (int c = 0; c < 2; ++c) {
      int ch = (w << 1) + c;
      int rowK = (ch << 2) + q16;                        // 4 rows / 1KB chunk
      int colbK = (l15 << 4) ^ ((rowK & 7) << 4);
      llds16(K + qkbase + (size_t)(s0 + rowK) * 2048 + (colbK >> 1), smem + kb + (ch << 10));
      int rowV = (ch << 4) + (lane >> 2);                // 16 rows / 1KB chunk
      int colbV = ((lane & 3) << 4) ^ (((rowV >> 2) & 3) << 4);
      llds16(V + vbase + (size_t)rowV * 2048 + s0 + (colbV >> 1), smem + vb + (ch << 10));
    }
  };

  // Q fragments: lane holds Q[t0 + (lane&15)][8*(lane>>4) + j + 32*kk]
  bf16x8 qf[4];
  {
    const unsigned short* qp = Q + qkbase + (size_t)(t0 + l15) * 2048 + (q16 << 3);
#pragma unroll
    for (int kk = 0; kk < 4; ++kk) qf[kk] = *(const bf16x8*)(qp + (kk << 5));
  }

  f32x4 oacc[8];
#pragma unroll
  for (int i = 0; i < 8; ++i) oacc[i] = (f32x4){0.f, 0.f, 0.f, 0.f};
  float ell[4] = {0.f, 0.f, 0.f, 0.f};   // per-lane partial; reduced in epilogue

  stage(0, 0, 16384);
  asm volatile("s_waitcnt vmcnt(0)" ::: "memory");
  __syncthreads();

  int cur = 0;
  for (int it = 0; it < numIter; ++it) {
    const int s0 = it << 5;
    if (it + 1 < numIter)
      stage(s0 + 32, (cur ^ 1) << 13, 16384 + ((cur ^ 1) << 13));

    if (s0 <= t0) {   // tile not entirely above this wave's diagonal
      const int kb = cur << 13;
      const int vb = 16384 + (cur << 13);

      // QK^T: two 16-col s-tiles (scores already scaled via Q)
      f32x4 sA = (f32x4){0.f, 0.f, 0.f, 0.f}, sB = (f32x4){0.f, 0.f, 0.f, 0.f};
#pragma unroll
      for (int kk = 0; kk < 4; ++kk) {
        int r0 = l15;
        bf16x8 k0f = *(const bf16x8*)(smem + kb + (r0 << 8) + (((kk << 6) + (q16 << 4)) ^ ((r0 & 7) << 4)));
        sA = __builtin_amdgcn_mfma_f32_16x16x32_bf16(qf[kk], k0f, sA, 0, 0, 0);
        int r1 = 16 + l15;
        bf16x8 k1f = *(const bf16x8*)(smem + kb + (r1 << 8) + (((kk << 6) + (q16 << 4)) ^ ((r1 & 7) << 4)));
        sB = __builtin_amdgcn_mfma_f32_16x16x32_bf16(qf[kk], k1f, sB, 0, 0, 0);
      }

      float pA[4], pB[4];
      if (s0 + 31 <= t0) {           // fully unmasked tile (the common case)
#pragma unroll
        for (int j = 0; j < 4; ++j) {
          pA[j] = __expf(sA[j]);
          pB[j] = __expf(sB[j]);
          ell[j] += pA[j] + pB[j];
        }
      } else {                       // straddling tile: mask -> exp(0)=1
#pragma unroll
        for (int j = 0; j < 4; ++j) {
          int t  = t0 + rb + j;
          int sa = s0 + l15;
          float vA = (sa <= t)      ? sA[j] : 0.f;
          float vB = (sa + 16 <= t) ? sB[j] : 0.f;
          pA[j] = __expf(vA);
          pB[j] = __expf(vB);
          ell[j] += pA[j] + pB[j];
        }
      }

      // P -> per-wave LDS [16 t][32 s] bf16, swz: col ^= ((row>>1)&3)<<4
#pragma unroll
      for (int j = 0; j < 4; ++j) {
        int r   = rb + j;
        int swz = ((r >> 1) & 3) << 4;
        *(unsigned short*)(Psm + (r << 6) + ((l15 << 1) ^ swz))        = f2bfru(pA[j]);
        *(unsigned short*)(Psm + (r << 6) + ((32 + (l15 << 1)) ^ swz)) = f2bfru(pB[j]);
      }
      asm volatile("s_waitcnt lgkmcnt(0)" ::: "memory");

      bf16x8 pa;
      {
        int r = l15;
        pa = *(const bf16x8*)(Psm + (r << 6) + ((q16 << 4) ^ (((r >> 1) & 3) << 4)));
      }
#pragma unroll
      for (int ni = 0; ni < 8; ++ni) {
        int dr = (ni << 4) + l15;
        bf16x8 vbf = *(const bf16x8*)(smem + vb + (dr << 6) + ((q16 << 4) ^ (((dr >> 2) & 3) << 4)));
        oacc[ni] = __builtin_amdgcn_mfma_f32_16x16x32_bf16(pa, vbf, oacc[ni], 0, 0, 0);
      }
    }

    asm volatile("s_waitcnt vmcnt(0)" ::: "memory");
    __syncthreads();
    cur ^= 1;
  }

  // suffix correction: all s >= send have p == 1 exactly.
  const int send = (t0 & ~31) + 32;
  const float* sp = Suf + (size_t)(send >> 5) * 4096 + ((size_t)bh << 7);
  const float extra = (float)(2048 - send);
#pragma unroll
  for (int ni = 0; ni < 8; ++ni) {
    float sv = sp[(ni << 4) + l15];
#pragma unroll
    for (int j = 0; j < 4; ++j) oacc[ni][j] += sv;
  }

  // deferred ell reduction (within each 16-lane row group), then normalize
#pragma unroll
  for (int j = 0; j < 4; ++j) {
    float r = ell[j];
    r += __shfl_xor(r, 1, 64);
    r += __shfl_xor(r, 2, 64);
    r += __shfl_xor(r, 4, 64);
    r += __shfl_xor(r, 8, 64);
    float inv = 1.0f / (r + extra);
    int t = t0 + rb + j;
    unsigned short* op = O + qkbase + (size_t)t * 2048;
#pragma unroll
    for (int ni = 0; ni < 8; ++ni)
      op[(ni << 4) + l15] = f2bf(oacc[ni][j] * inv);
  }
}

// ---------------------------------------------------------------------------
// launch
// ---------------------------------------------------------------------------
extern "C" void kernel_launch(void* const* d_in, const int* in_sizes, int n_in,
                              void* d_out, int out_size, void* d_ws, size_t ws_size,
                              hipStream_t stream) {
  (void)in_sizes; (void)n_in; (void)out_size; (void)ws_size;
  const float* x  = (const float*)d_in[0];
  const float* Wq = (const float*)d_in[1];
  const float* Wk = (const float*)d_in[2];
  const float* Wv = (const float*)d_in[3];
  const float* Wo = (const float*)d_in[4];
  float* out = (float*)d_out;

  char* ws = (char*)d_ws;
  unsigned short* Xb  = (unsigned short*)(ws);                        // 16 MiB (reused as O)
  unsigned short* Wqt = (unsigned short*)(ws + 16777216);             // 8 MiB (reused as Suf)
  unsigned short* Wkt = (unsigned short*)(ws + 16777216 + 8388608);
  unsigned short* Wvt = (unsigned short*)(ws + 16777216 + 2 * 8388608);
  unsigned short* Wot = (unsigned short*)(ws + 16777216 + 3 * 8388608);
  unsigned short* Qb  = (unsigned short*)(ws + 50331648);             // 16 MiB
  unsigned short* Kb  = (unsigned short*)(ws + 67108864);             // 16 MiB
  unsigned short* Vt  = (unsigned short*)(ws + 83886080);             // 16 MiB
  unsigned short* Ob  = Xb;          // X dead after the QKV projection
  float*          Suf = (float*)Wqt; // W^T dead after the QKV projection

  cast_x_kernel<<<8192, 256, 0, stream>>>(x, Xb);
  {
    dim3 tb(32, 8), tg(64, 64, 4);
    transpose_w4_kernel<<<tg, tb, 0, stream>>>(Wq, Wk, Wv, Wo, Wqt, Wkt, Wvt, Wot);
  }
  // fused QKV projection: Bt = [Wqt|Wkt|Wvt] (contiguous), N=6144
  gemm_qkv8p<<<384, 512, 0, stream>>>(Xb, Wqt, Qb, Kb, Vt);

  vsuf_kernel<<<1024, 256, 0, stream>>>(Vt, Suf);

  attn_kernel<<<1024, 256, 0, stream>>>(Qb, Kb, Vt, Suf, Ob);

  gemm_wo<<<512, 256, 0, stream>>>(Ob, Wot, out);
}

// Round 12
// 260.216 us; speedup vs baseline: 1.0878x; 1.0878x over previous
//
#include <hip/hip_runtime.h>

// ---------------------------------------------------------------------------
// MultiHeadAttention forward, MI355X/gfx950.
// B=2, T=2048, D=2048, H=16, Dh=128. fp32 in/out, bf16 MFMA internally.
// Reference quirks (faithful): multiplicative tril mask (masked scores = 0,
// NOT -inf -> exp(0)=1 contributions over ALL 2048 cols), scale = 1/sqrt(T).
// Round 12: QKV GEMM reverted to round-8 best (ring-3, counted vmcnt(6),
// 120.9us measured). Attention rewritten QBLK=32/wave: 128-row blocks,
// 32 MFMA + 16 exp per sync cycle (2x), K/V/P fragments reused across the
// two q-subtiles, complementary-strip pairing for CU load balance.
// ---------------------------------------------------------------------------

typedef __attribute__((ext_vector_type(4))) float  f32x4;
typedef __attribute__((ext_vector_type(8))) short  bf16x8;
typedef __attribute__((ext_vector_type(4))) unsigned short u16x4;

#define AS1 __attribute__((address_space(1)))
#define AS3 __attribute__((address_space(3)))

__device__ __forceinline__ void llds16(const void* g, void* l) {
  __builtin_amdgcn_global_load_lds((const AS1 void*)g, (AS3 void*)l, 16, 0, 0);
}

__device__ __forceinline__ unsigned short f2bf(float f) {   // RNE
  unsigned int u = __builtin_bit_cast(unsigned int, f);
  u += 0x7fffu + ((u >> 16) & 1u);
  return (unsigned short)(u >> 16);
}

__device__ __forceinline__ unsigned short f2bfru(float f) { // round-half-up
  return (unsigned short)((__builtin_bit_cast(unsigned int, f) + 0x8000u) >> 16);
}

__device__ __forceinline__ float bf2f(unsigned short u) {
  return __builtin_bit_cast(float, (unsigned int)u << 16);
}

// ---------------------------------------------------------------------------
// cast x (fp32) -> bf16, 4 elements/thread
// ---------------------------------------------------------------------------
__global__ __launch_bounds__(256) void cast_x_kernel(const float* __restrict__ in,
                                                     unsigned short* __restrict__ out) {
  int i = blockIdx.x * 256 + threadIdx.x;
  f32x4 v = ((const f32x4*)in)[i];
  u16x4 o;
  o[0] = f2bf(v[0]); o[1] = f2bf(v[1]); o[2] = f2bf(v[2]); o[3] = f2bf(v[3]);
  ((u16x4*)out)[i] = o;
}

// ---------------------------------------------------------------------------
// 4 weight transposes in one launch. W [2048][2048] fp32 -> Wt[n][k] bf16.
// ---------------------------------------------------------------------------
__global__ __launch_bounds__(256) void transpose_w4_kernel(
    const float* __restrict__ W0, const float* __restrict__ W1,
    const float* __restrict__ W2, const float* __restrict__ W3,
    unsigned short* __restrict__ T0, unsigned short* __restrict__ T1,
    unsigned short* __restrict__ T2, unsigned short* __restrict__ T3) {
  __shared__ float tile[32][33];
  const int z = blockIdx.z;
  const float* W = (z == 0) ? W0 : (z == 1) ? W1 : (z == 2) ? W2 : W3;
  unsigned short* Wt = (z == 0) ? T0 : (z == 1) ? T1 : (z == 2) ? T2 : T3;
  const int bx = blockIdx.x << 5;   // k base
  const int by = blockIdx.y << 5;   // n base
  const int tx = threadIdx.x;       // 0..31
  const int ty = threadIdx.y;       // 0..7
#pragma unroll
  for (int r = ty; r < 32; r += 8)
    tile[r][tx] = W[(size_t)(bx + r) * 2048 + by + tx];
  __syncthreads();
#pragma unroll
  for (int r = ty; r < 32; r += 8)
    Wt[(size_t)(by + r) * 2048 + bx + tx] = f2bf(tile[tx][r]);
}

// ---------------------------------------------------------------------------
// Fused QKV projection GEMM (round-8 best: 120.9us). Ring-3 depth-2 prefetch.
// C[M=4096][N=6144] = X[M][K=2048] @ Wt[N][K]^T, Wt = [Wq^T|Wk^T|Wv^T].
// BM=128, BN=256, BK=64. 8 waves (2M x 4N), wave tile 64x64 (4mi x 4ni).
// LDS: 3 slots x (A 16KB + B 32KB) = 144KB. Per K-tile: [vmcnt(6) ->
// s_barrier] ; stage(kt+2) ; 2 x { read 8 frags, 16 MFMA } free-running.
// Rows 128B = 8 chunks of 16B, chunk swizzle c ^= row&7 both sides.
// Grid 768 flat = 3 exact CU rounds; 3 bn panels per XCD (3MB -> L2).
// ---------------------------------------------------------------------------
__global__ __launch_bounds__(512, 2) void gemm_qkv(const unsigned short* __restrict__ A,
                                                   const unsigned short* __restrict__ Bt,
                                                   unsigned short* __restrict__ Qb,
                                                   unsigned short* __restrict__ Kb,
                                                   unsigned short* __restrict__ Vt) {
  constexpr int SLOT = 49152;                 // A 16384 + B 32768
  __shared__ __align__(16) char smem[3 * SLOT];
  const int tid  = threadIdx.x;
  const int lane = tid & 63;
  const int w    = tid >> 6;          // 0..7
  const int wr   = w >> 2;            // m-half (0..1)
  const int wc   = w & 3;             // n-quarter (0..3)
  const int q16  = lane >> 4;
  const int l15  = lane & 15;
  const int f    = blockIdx.x;
  const int g    = f >> 3;                        // 0..95
  const int bn   = (f & 7) * 3 + (g % 3);         // 0..23
  const int bm   = g / 3;                         // 0..31

  const int srow = tid >> 3;                      // 0..63
  const int scl  = (tid & 7) ^ (srow & 7);
  const unsigned short* aS = A  + (size_t)((bm << 7) + srow) * 2048 + (scl << 3);
  const unsigned short* bS = Bt + (size_t)(bn * 256 + srow) * 2048 + (scl << 3);
  const int sdst = tid << 4;

  // ds_read: row = base + l15, chunk = (ks*4 + q16) ^ (l15&7)
  const int swzb = (q16 ^ (l15 & 7)) << 4;        // ks=1: ^ 64
  const int aRd  = ((wr << 6) + l15) << 7;        // + mi*2048

  f32x4 acc[4][4];
#pragma unroll
  for (int i = 0; i < 4; ++i)
#pragma unroll
    for (int j = 0; j < 4; ++j) acc[i][j] = (f32x4){0.f, 0.f, 0.f, 0.f};

  auto stageT = [&](int kt, char* sb) {
    const size_t ko = (size_t)kt << 6;            // k element offset
    llds16(aS + ko,               sb + sdst);
    llds16(aS + (64 * 2048) + ko, sb + 8192 + sdst);
#pragma unroll
    for (int r = 0; r < 4; ++r)
      llds16(bS + (size_t)r * (64 * 2048) + ko, sb + 16384 + (r << 13) + sdst);
  };

  auto computeT = [&](const char* base) {
#pragma unroll
    for (int ks = 0; ks < 2; ++ks) {
      const int sw = swzb ^ (ks << 6);
      bf16x8 af[4], bf[4];
#pragma unroll
      for (int mi = 0; mi < 4; ++mi)
        af[mi] = *(const bf16x8*)(base + aRd + (mi << 11) + sw);
#pragma unroll
      for (int ni = 0; ni < 4; ++ni)
        bf[ni] = *(const bf16x8*)(base + 16384 + (((wc << 6) + l15) << 7) + (ni << 11) + sw);
      __builtin_amdgcn_s_setprio(1);
#pragma unroll
      for (int mi = 0; mi < 4; ++mi)
#pragma unroll
        for (int ni = 0; ni < 4; ++ni)
          acc[mi][ni] = __builtin_amdgcn_mfma_f32_16x16x32_bf16(af[mi], bf[ni], acc[mi][ni], 0, 0, 0);
      __builtin_amdgcn_s_setprio(0);
    }
  };

  char* s0 = smem;
  char* s1 = smem + SLOT;
  char* s2 = smem + 2 * SLOT;

#define W6()  asm volatile("s_waitcnt vmcnt(6)" ::: "memory")
#define W0()  asm volatile("s_waitcnt vmcnt(0)" ::: "memory")
#define BAR() __builtin_amdgcn_s_barrier()

  stageT(0, s0); stageT(1, s1);
  W6(); BAR();
  stageT(2, s2);
  computeT(s0);
#pragma unroll 1
  for (int b = 1; b <= 25; b += 3) {
    W6(); BAR(); stageT(b + 2, s0); computeT(s1);
    W6(); BAR(); stageT(b + 3, s1); computeT(s2);
    W6(); BAR(); stageT(b + 4, s2); computeT(s0);
  }
  W6(); BAR(); stageT(30, s0); computeT(s1);
  W6(); BAR(); stageT(31, s1); computeT(s2);
  W6(); BAR(); computeT(s0);
  W0(); BAR(); computeT(s1);

#undef W6
#undef W0
#undef BAR

  // epilogue. C/D layout: col = lane&15, row = (lane>>4)*4 + reg  [m89]
  const float qscale = 0.02209708691207961f;   // 1/sqrt(2048)
  const int rb = q16 << 2;
#pragma unroll
  for (int mi = 0; mi < 4; ++mi) {
    int m0 = (bm << 7) + (wr << 6) + (mi << 4) + rb;
#pragma unroll
    for (int ni = 0; ni < 4; ++ni) {
      int gn = (bn << 8) + (wc << 6) + (ni << 4) + l15;
      int region = gn >> 11;                     // 0 Q, 1 K, 2 V
      int nloc = gn & 2047;
      if (region == 0) {
#pragma unroll
        for (int j = 0; j < 4; ++j)
          Qb[(size_t)(m0 + j) * 2048 + nloc] = f2bf(acc[mi][ni][j] * qscale);
      } else if (region == 1) {
#pragma unroll
        for (int j = 0; j < 4; ++j)
          Kb[(size_t)(m0 + j) * 2048 + nloc] = f2bf(acc[mi][ni][j]);
      } else {
        u16x4 pk;
#pragma unroll
        for (int j = 0; j < 4; ++j) pk[j] = f2bf(acc[mi][ni][j]);
        int b = m0 >> 11, t = m0 & 2047;
        *(u16x4*)(Vt + ((size_t)((b << 4) + (nloc >> 7)) * 128 + (nloc & 127)) * 2048 + t) = pk;
      }
    }
  }
}

// ---------------------------------------------------------------------------
// Wo GEMM (passing): C fp32 = A[M][K] @ Bt[N][K]^T. BM=128, BN=128,
// wave tile 64x64 (2Mx2N), 4 waves, BK=32, ring-3 LDS, grid 512.
// ---------------------------------------------------------------------------
__global__ __launch_bounds__(256, 2) void gemm_wo(const unsigned short* __restrict__ A,
                                                  const unsigned short* __restrict__ Bt,
                                                  float* __restrict__ Co) {
  constexpr int SLOT = 8192 + 8192;
  __shared__ __align__(16) char smem[3 * SLOT];

  const int tid  = threadIdx.x;
  const int lane = tid & 63;
  const int w    = tid >> 6;                        // 0..3
  const int q16  = lane >> 4;
  const int l15  = lane & 15;
  const int f    = blockIdx.x;
  const int g    = f >> 3;
  const int bn   = ((f & 7) << 1) + (g & 1);
  const int bm   = g >> 1;
  const int wmb  = (w >> 1) << 6;
  const int wnb  = (w & 1) << 6;

  f32x4 acc[4][4];
#pragma unroll
  for (int i = 0; i < 4; ++i)
#pragma unroll
    for (int j = 0; j < 4; ++j) acc[i][j] = (f32x4){0.f, 0.f, 0.f, 0.f};

  const int rowA = tid >> 2;
  const int chA  = tid & 3;
  auto stageT = [&](int t, char* sb) {
    const int k0 = t << 5;
#pragma unroll
    for (int r = 0; r < 2; ++r) {
      int row = (r << 6) + rowA;
      const unsigned short* src = A + (size_t)((bm << 7) + row) * 2048 + k0
                                    + ((chA ^ ((row >> 1) & 3)) << 3);
      llds16(src, sb + (r << 12) + (w << 10));
    }
#pragma unroll
    for (int r = 0; r < 2; ++r) {
      int row = (r << 6) + rowA;
      const unsigned short* src = Bt + (size_t)((bn << 7) + row) * 2048 + k0
                                     + ((chA ^ ((row >> 1) & 3)) << 3);
      llds16(src, sb + 8192 + (r << 12) + (w << 10));
    }
  };

  auto computeT = [&](const char* base) {
    bf16x8 af[4], bf[4];
#pragma unroll
    for (int mi = 0; mi < 4; ++mi) {
      int row = wmb + (mi << 4) + l15;
      af[mi] = *(const bf16x8*)(base + (row << 6) + ((q16 ^ ((row >> 1) & 3)) << 4));
    }
#pragma unroll
    for (int ni = 0; ni < 4; ++ni) {
      int row = wnb + (ni << 4) + l15;
      bf[ni] = *(const bf16x8*)(base + 8192 + (row << 6) + ((q16 ^ ((row >> 1) & 3)) << 4));
    }
    __builtin_amdgcn_s_setprio(1);
#pragma unroll
    for (int mi = 0; mi < 4; ++mi)
#pragma unroll
      for (int ni = 0; ni < 4; ++ni)
        acc[mi][ni] = __builtin_amdgcn_mfma_f32_16x16x32_bf16(af[mi], bf[ni], acc[mi][ni], 0, 0, 0);
    __builtin_amdgcn_s_setprio(0);
  };

  auto STEP = [&](int t, char* cbase, char* sbase) {
    asm volatile("s_waitcnt vmcnt(4)" ::: "memory");
    __builtin_amdgcn_s_barrier();
    stageT(t + 2, sbase);
    computeT(cbase);
  };

  char* s0 = smem;
  char* s1 = smem + SLOT;
  char* s2 = smem + 2 * SLOT;

  stageT(0, s0); stageT(1, s1);
#pragma unroll 1
  for (int t = 0; t < 60; t += 3) {
    STEP(t,     s0, s2);
    STEP(t + 1, s1, s0);
    STEP(t + 2, s2, s1);
  }
  STEP(60, s0, s2);
  STEP(61, s1, s0);
  asm volatile("s_waitcnt vmcnt(4)" ::: "memory");
  __builtin_amdgcn_s_barrier();
  computeT(s2);
  asm volatile("s_waitcnt vmcnt(0)" ::: "memory");
  __builtin_amdgcn_s_barrier();
  computeT(s0);

  const int rb = q16 << 2;
#pragma unroll
  for (int mi = 0; mi < 4; ++mi) {
    int m0 = (bm << 7) + wmb + (mi << 4) + rb;
#pragma unroll
    for (int ni = 0; ni < 4; ++ni) {
      int n = (bn << 7) + wnb + (ni << 4) + l15;
#pragma unroll
      for (int j = 0; j < 4; ++j)
        Co[(size_t)(m0 + j) * 2048 + n] = acc[mi][ni][j];
    }
  }
}

// ---------------------------------------------------------------------------
// V suffix sums at 32-row granularity.
// Suf[j][bh][d] = sum_{s >= 32j} V[b, s, h, d],  j in 0..64 (Suf[64] = 0).
// ---------------------------------------------------------------------------
__global__ __launch_bounds__(256) void vsuf_kernel(const unsigned short* __restrict__ Vt,
                                                   float* __restrict__ Suf) {
  const int row  = blockIdx.x * 4 + (threadIdx.x >> 6);  // 0..4095
  const int lane = threadIdx.x & 63;
  const unsigned short* vp = Vt + (size_t)row * 2048 + (lane << 5);
  float a = 0.f;
#pragma unroll
  for (int c = 0; c < 4; ++c) {
    bf16x8 v = *(const bf16x8*)(vp + (c << 3));
#pragma unroll
    for (int j = 0; j < 8; ++j) a += bf2f((unsigned short)v[j]);
  }
  float I = a;
#pragma unroll
  for (int off = 1; off < 64; off <<= 1) {
    float t = __shfl_down(I, off, 64);
    I += (lane + off < 64) ? t : 0.f;
  }
  Suf[(size_t)lane * 4096 + row] = I;
  if (lane == 0) Suf[(size_t)64 * 4096 + row] = 0.f;
}

// ---------------------------------------------------------------------------
// Fused attention, QBLK=32/wave. Block = 4 waves x 32 q-rows = 128-row strip.
// Grid 512 = 32 bh x 16 strips. Decode: xcd = f&7, bh = xcd*4 + ((f>>3)&3);
// strip = (f>>5 < 8) ? 15-(f>>5) : (f>>5)-8  -> the two blocks a CU hosts
// have complementary strips (uniform 68-iteration pairs).
// Q PRE-SCALED by 1/sqrt(T). Per 32-s tile (dbuf): 16 QK MFMA (K-frags
// shared by both q-subtiles), 16 exp, P[32][32] pack, 16 PV MFMA (V-frags
// shared). Mask only on the straddling tile (s0 == t0); s0 < t0 tiles are
// fully unmasked; s >= t0+32 covered by the V-suffix sums (p == 1 exactly).
// ---------------------------------------------------------------------------
__global__ __launch_bounds__(256, 2) void attn_kernel(const unsigned short* __restrict__ Q,
                                                      const unsigned short* __restrict__ K,
                                                      const unsigned short* __restrict__ V,  // Vt layout
                                                      const float* __restrict__ Suf,
                                                      unsigned short* __restrict__ O) {
  __shared__ __align__(16) char smem[40960];  // K dbuf 2x8K | V dbuf 2x8K | P 4x2K
  const int tid  = threadIdx.x;
  const int lane = tid & 63;
  const int w    = tid >> 6;
  const int q16  = lane >> 4;
  const int l15  = lane & 15;
  const int f    = blockIdx.x;
  const int bh   = ((f & 7) << 2) + ((f >> 3) & 3);
  const int fs   = f >> 5;                            // 0..15
  const int strip = (fs < 8) ? (15 - fs) : (fs - 8);  // complementary pairing
  const int b  = bh >> 4;
  const size_t qkbase = ((size_t)(b << 11)) * 2048 + ((size_t)(bh & 15) << 7);
  const size_t vbase  = (size_t)bh << 18;     // bh*128*2048
  const int rb = q16 << 2;
  char* Psm = smem + 32768 + (w << 11);       // 2KB per wave

  const int numIter = 4 * strip + 4;
  const int t0 = (strip << 7) + (w << 5);     // wave's 32-row base (mult of 32)

  auto stage = [&](int s0, int kb, int vb) {
#pragma unroll
    for (int c = 0; c < 2; ++c) {
      int ch = (w << 1) + c;
      int rowK = (ch << 2) + q16;                        // 4 rows / 1KB chunk
      int colbK = (l15 << 4) ^ ((rowK & 7) << 4);
      llds16(K + qkbase + (size_t)(s0 + rowK) * 2048 + (colbK >> 1), smem + kb + (ch << 10));
      int rowV = (ch << 4) + (lane >> 2);                // 16 rows / 1KB chunk
      int colbV = ((lane & 3) << 4) ^ (((rowV >> 2) & 3) << 4);
      llds16(V + vbase + (size_t)rowV * 2048 + s0 + (colbV >> 1), smem + vb + (ch << 10));
    }
  };

  // Q fragments, both subtiles (rows t0.. and t0+16..)
  bf16x8 qf[4], qg[4];
  {
    const unsigned short* qp = Q + qkbase + (size_t)(t0 + l15) * 2048 + (q16 << 3);
#pragma unroll
    for (int kk = 0; kk < 4; ++kk) qf[kk] = *(const bf16x8*)(qp + (kk << 5));
    const unsigned short* qp2 = qp + (size_t)16 * 2048;
#pragma unroll
    for (int kk = 0; kk < 4; ++kk) qg[kk] = *(const bf16x8*)(qp2 + (kk << 5));
  }

  f32x4 oA[8], oB[8];
#pragma unroll
  for (int i = 0; i < 8; ++i) { oA[i] = (f32x4){0.f,0.f,0.f,0.f}; oB[i] = (f32x4){0.f,0.f,0.f,0.f}; }
  float ellA[4] = {0.f,0.f,0.f,0.f}, ellB[4] = {0.f,0.f,0.f,0.f};

  stage(0, 0, 16384);
  asm volatile("s_waitcnt vmcnt(0)" ::: "memory");
  __syncthreads();

  int cur = 0;
  for (int it = 0; it < numIter; ++it) {
    const int s0 = it << 5;
    if (it + 1 < numIter)
      stage(s0 + 32, (cur ^ 1) << 13, 16384 + ((cur ^ 1) << 13));

    if (s0 <= t0) {   // tile not entirely above this wave's 32 rows
      const int kb = cur << 13;
      const int vb = 16384 + (cur << 13);

      // QK^T: K-frags shared by both q-subtiles (16 MFMA)
      f32x4 sA = (f32x4){0.f,0.f,0.f,0.f}, sB = sA, sC = sA, sD = sA;
#pragma unroll
      for (int kk = 0; kk < 4; ++kk) {
        int r0 = l15, r1 = 16 + l15;
        bf16x8 k0f = *(const bf16x8*)(smem + kb + (r0 << 8) + (((kk << 6) + (q16 << 4)) ^ ((r0 & 7) << 4)));
        bf16x8 k1f = *(const bf16x8*)(smem + kb + (r1 << 8) + (((kk << 6) + (q16 << 4)) ^ ((r1 & 7) << 4)));
        sA = __builtin_amdgcn_mfma_f32_16x16x32_bf16(qf[kk], k0f, sA, 0, 0, 0);
        sC = __builtin_amdgcn_mfma_f32_16x16x32_bf16(qg[kk], k0f, sC, 0, 0, 0);
        sB = __builtin_amdgcn_mfma_f32_16x16x32_bf16(qf[kk], k1f, sB, 0, 0, 0);
        sD = __builtin_amdgcn_mfma_f32_16x16x32_bf16(qg[kk], k1f, sD, 0, 0, 0);
      }

      float pA[4], pB[4], pC[4], pD[4];
      if (s0 + 32 <= t0) {           // fully unmasked tile (common case)
#pragma unroll
        for (int j = 0; j < 4; ++j) {
          pA[j] = __expf(sA[j]); pB[j] = __expf(sB[j]);
          pC[j] = __expf(sC[j]); pD[j] = __expf(sD[j]);
          ellA[j] += pA[j] + pB[j];
          ellB[j] += pC[j] + pD[j];
        }
      } else {                       // straddling tile (s0 == t0): mask -> exp(0)=1
#pragma unroll
        for (int j = 0; j < 4; ++j) {
          int tA = t0 + rb + j, tB = tA + 16;
          int sa = s0 + l15;
          float vA = (sa <= tA)      ? sA[j] : 0.f;
          float vB = (sa + 16 <= tA) ? sB[j] : 0.f;
          float vC = (sa <= tB)      ? sC[j] : 0.f;
          float vD = (sa + 16 <= tB) ? sD[j] : 0.f;
          pA[j] = __expf(vA); pB[j] = __expf(vB);
          pC[j] = __expf(vC); pD[j] = __expf(vD);
          ellA[j] += pA[j] + pB[j];
          ellB[j] += pC[j] + pD[j];
        }
      }

      // P -> per-wave LDS [32 t][32 s] bf16, swz: col ^= ((row>>1)&3)<<4
#pragma unroll
      for (int j = 0; j < 4; ++j) {
        int rA = rb + j;
        int swzA = ((rA >> 1) & 3) << 4;
        *(unsigned short*)(Psm + (rA << 6) + ((l15 << 1) ^ swzA))        = f2bfru(pA[j]);
        *(unsigned short*)(Psm + (rA << 6) + ((32 + (l15 << 1)) ^ swzA)) = f2bfru(pB[j]);
        int rB = rA + 16;
        int swzB = ((rB >> 1) & 3) << 4;
        *(unsigned short*)(Psm + (rB << 6) + ((l15 << 1) ^ swzB))        = f2bfru(pC[j]);
        *(unsigned short*)(Psm + (rB << 6) + ((32 + (l15 << 1)) ^ swzB)) = f2bfru(pD[j]);
      }
      asm volatile("s_waitcnt lgkmcnt(0)" ::: "memory");

      bf16x8 paA, paB;
      {
        int r = l15;
        paA = *(const bf16x8*)(Psm + (r << 6) + ((q16 << 4) ^ (((r >> 1) & 3) << 4)));
        int r2 = 16 + l15;
        paB = *(const bf16x8*)(Psm + (r2 << 6) + ((q16 << 4) ^ (((r2 >> 1) & 3) << 4)));
      }
      // PV: V-frags shared by both q-subtiles (16 MFMA)
#pragma unroll
      for (int ni = 0; ni < 8; ++ni) {
        int dr = (ni << 4) + l15;
        bf16x8 vbf = *(const bf16x8*)(smem + vb + (dr << 6) + ((q16 << 4) ^ (((dr >> 2) & 3) << 4)));
        oA[ni] = __builtin_amdgcn_mfma_f32_16x16x32_bf16(paA, vbf, oA[ni], 0, 0, 0);
        oB[ni] = __builtin_amdgcn_mfma_f32_16x16x32_bf16(paB, vbf, oB[ni], 0, 0, 0);
      }
    }

    asm volatile("s_waitcnt vmcnt(0)" ::: "memory");
    __syncthreads();
    cur ^= 1;
  }

  // suffix correction: all s >= send have p == 1 exactly (both subtiles).
  const int send = t0 + 32;
  const float* sp = Suf + (size_t)(send >> 5) * 4096 + ((size_t)bh << 7);
  const float extra = (float)(2048 - send);
#pragma unroll
  for (int ni = 0; ni < 8; ++ni) {
    float sv = sp[(ni << 4) + l15];
#pragma unroll
    for (int j = 0; j < 4; ++j) { oA[ni][j] += sv; oB[ni][j] += sv; }
  }

  // deferred ell reductions, then normalize + store (both subtiles)
#pragma unroll
  for (int j = 0; j < 4; ++j) {
    float r = ellA[j];
    r += __shfl_xor(r, 1, 64);
    r += __shfl_xor(r, 2, 64);
    r += __shfl_xor(r, 4, 64);
    r += __shfl_xor(r, 8, 64);
    float inv = 1.0f / (r + extra);
    int t = t0 + rb + j;
    unsigned short* op = O + qkbase + (size_t)t * 2048;
#pragma unroll
    for (int ni = 0; ni < 8; ++ni)
      op[(ni << 4) + l15] = f2bf(oA[ni][j] * inv);

    float r2 = ellB[j];
    r2 += __shfl_xor(r2, 1, 64);
    r2 += __shfl_xor(r2, 2, 64);
    r2 += __shfl_xor(r2, 4, 64);
    r2 += __shfl_xor(r2, 8, 64);
    float inv2 = 1.0f / (r2 + extra);
    unsigned short* op2 = op + (size_t)16 * 2048;
#pragma unroll
    for (int ni = 0; ni < 8; ++ni)
      op2[(ni << 4) + l15] = f2bf(oB[ni][j] * inv2);
  }
}

// ---------------------------------------------------------------------------
// launch
// ---------------------------------------------------------------------------
extern "C" void kernel_launch(void* const* d_in, const int* in_sizes, int n_in,
                              void* d_out, int out_size, void* d_ws, size_t ws_size,
                              hipStream_t stream) {
  (void)in_sizes; (void)n_in; (void)out_size; (void)ws_size;
  const float* x  = (const float*)d_in[0];
  const float* Wq = (const float*)d_in[1];
  const float* Wk = (const float*)d_in[2];
  const float* Wv = (const float*)d_in[3];
  const float* Wo = (const float*)d_in[4];
  float* out = (float*)d_out;

  char* ws = (char*)d_ws;
  unsigned short* Xb  = (unsigned short*)(ws);                        // 16 MiB (reused as O)
  unsigned short* Wqt = (unsigned short*)(ws + 16777216);             // 8 MiB (reused as Suf)
  unsigned short* Wkt = (unsigned short*)(ws + 16777216 + 8388608);
  unsigned short* Wvt = (unsigned short*)(ws + 16777216 + 2 * 8388608);
  unsigned short* Wot = (unsigned short*)(ws + 16777216 + 3 * 8388608);
  unsigned short* Qb  = (unsigned short*)(ws + 50331648);             // 16 MiB
  unsigned short* Kb  = (unsigned short*)(ws + 67108864);             // 16 MiB
  unsigned short* Vt  = (unsigned short*)(ws + 83886080);             // 16 MiB
  unsigned short* Ob  = Xb;          // X dead after the QKV projection
  float*          Suf = (float*)Wqt; // W^T dead after the QKV projection

  cast_x_kernel<<<8192, 256, 0, stream>>>(x, Xb);
  {
    dim3 tb(32, 8), tg(64, 64, 4);
    transpose_w4_kernel<<<tg, tb, 0, stream>>>(Wq, Wk, Wv, Wo, Wqt, Wkt, Wvt, Wot);
  }
  // fused QKV projection: Bt = [Wqt|Wkt|Wvt] (contiguous), N=6144
  gemm_qkv<<<768, 512, 0, stream>>>(Xb, Wqt, Qb, Kb, Vt);

  vsuf_kernel<<<1024, 256, 0, stream>>>(Vt, Suf);

  attn_kernel<<<512, 256, 0, stream>>>(Qb, Kb, Vt, Suf, Ob);

  gemm_wo<<<512, 256, 0, stream>>>(Ob, Wot, out);
}